// Round 2
// baseline (270.678 us; speedup 1.0000x reference)
//
#include <hip/hip_runtime.h>

typedef __attribute__((ext_vector_type(8))) __bf16 bf16x8;
typedef __attribute__((ext_vector_type(4))) float f32x4;
typedef __attribute__((ext_vector_type(8))) unsigned short u16x8;

#define MFMA16(a, b, c) __builtin_amdgcn_mfma_f32_16x16x32_bf16((a), (b), (c), 0, 0, 0)

__device__ __forceinline__ unsigned short f2bf(float f) {
    union { float f; unsigned int u; } v;
    v.f = f;
    unsigned int u = v.u;
    unsigned int r = (u + 0x7fffu + ((u >> 16) & 1u)) >> 16;
    return (unsigned short)r;
}

// ---------------------------------------------------------------- convert f32 -> bf16
__global__ void convert_f32_bf16(const float* __restrict__ src, unsigned short* __restrict__ dst, int n4) {
    int i = blockIdx.x * blockDim.x + threadIdx.x;
    if (i < n4) {
        float4 v = reinterpret_cast<const float4*>(src)[i];
        ushort4 o;
        o.x = f2bf(v.x); o.y = f2bf(v.y); o.z = f2bf(v.z); o.w = f2bf(v.w);
        reinterpret_cast<ushort4*>(dst)[i] = o;
    }
}

// ---------------------------------------------------------------- WkE / WvF fold (tiny)
__global__ void build_wkev(const float* __restrict__ Wk, const float* __restrict__ Wv,
                           const float* __restrict__ E, const float* __restrict__ F,
                           unsigned short* __restrict__ wcat) {
    int idx = blockIdx.x * 256 + threadIdx.x;          // 2M threads
    int c   = idx & 1023;
    int n2  = (idx >> 10) & 1023;
    int sel = idx >> 20;                                // 0 -> WkE, 1 -> WvF
    int h = n2 >> 6, kk = n2 & 63;
    const float* W  = sel ? Wv : Wk;
    const float* Ef = sel ? F : E;
    float acc = 0.f;
#pragma unroll 8
    for (int d = 0; d < 64; ++d)
        acc += W[(size_t)((h * 64 + d)) * 1024 + c] * Ef[(h * 64 + d) * 64 + kk];
    wcat[(size_t)(1024 + (sel << 10) + n2) * 1024 + c] = f2bf(acc);
}

// ---------------------------------------------------------------- bf16 GEMM, B^T layout
template <int MODE>
__global__ __launch_bounds__(256) void gemm_bt(
    const unsigned short* __restrict__ A, const unsigned short* __restrict__ Bt, int K,
    unsigned short* __restrict__ qo, unsigned short* __restrict__ kpo, unsigned short* __restrict__ vpto,
    float* __restrict__ out, const float* __restrict__ bp) {
    __shared__ __align__(16) unsigned short As[128 * 32];
    __shared__ __align__(16) unsigned short Bs[128 * 32];
    const int tid = threadIdx.x;
    const int lane = tid & 63, wv = tid >> 6;
    const int g = lane >> 4, ln = lane & 15;
    const int wm = wv >> 1, wn = wv & 1;
    const int m0 = blockIdx.x * 128, n0 = blockIdx.y * 128;

    f32x4 acc[4][4];
#pragma unroll
    for (int i = 0; i < 4; ++i)
#pragma unroll
        for (int j = 0; j < 4; ++j) acc[i][j] = (f32x4){0.f, 0.f, 0.f, 0.f};

    const int c0 = tid, c1 = 256 + tid;
    const int row0 = c0 >> 2, k80 = c0 & 3;
    const int row1 = c1 >> 2, k81 = c1 & 3;

    const int nk = K >> 5;
    for (int kt = 0; kt < nk; ++kt) {
        const int kb = kt * 32;
        u16x8 ra0 = *reinterpret_cast<const u16x8*>(A + (size_t)(m0 + row0) * K + kb + k80 * 8);
        u16x8 ra1 = *reinterpret_cast<const u16x8*>(A + (size_t)(m0 + row1) * K + kb + k81 * 8);
        u16x8 rb0 = *reinterpret_cast<const u16x8*>(Bt + (size_t)(n0 + row0) * K + kb + k80 * 8);
        u16x8 rb1 = *reinterpret_cast<const u16x8*>(Bt + (size_t)(n0 + row1) * K + kb + k81 * 8);
        __syncthreads();
        *reinterpret_cast<u16x8*>(As + c0 * 8) = ra0;
        *reinterpret_cast<u16x8*>(As + c1 * 8) = ra1;
        *reinterpret_cast<u16x8*>(Bs + c0 * 8) = rb0;
        *reinterpret_cast<u16x8*>(Bs + c1 * 8) = rb1;
        __syncthreads();
        bf16x8 af[4], bfr[4];
#pragma unroll
        for (int i = 0; i < 4; ++i)
            af[i] = __builtin_bit_cast(bf16x8, *reinterpret_cast<const u16x8*>(As + (wm * 64 + i * 16 + ln) * 32 + g * 8));
#pragma unroll
        for (int j = 0; j < 4; ++j)
            bfr[j] = __builtin_bit_cast(bf16x8, *reinterpret_cast<const u16x8*>(Bs + (wn * 64 + j * 16 + ln) * 32 + g * 8));
#pragma unroll
        for (int i = 0; i < 4; ++i)
#pragma unroll
            for (int j = 0; j < 4; ++j)
                acc[i][j] = MFMA16(af[i], bfr[j], acc[i][j]);
    }

#pragma unroll
    for (int i = 0; i < 4; ++i) {
        const int mbase = m0 + wm * 64 + i * 16 + 4 * g;
#pragma unroll
        for (int j = 0; j < 4; ++j) {
            const int ncol = n0 + wn * 64 + j * 16 + ln;
#pragma unroll
            for (int r = 0; r < 4; ++r) {
                const int m = mbase + r;
                if (MODE == 0) {
                    const int b = m >> 11, t = m & 2047;
                    const int sec = ncol >> 10, nn = ncol & 1023;
                    const int h = nn >> 6, e = nn & 63;
                    const int bh = b * 16 + h;
                    unsigned short val = f2bf(acc[i][j][r]);
                    if (sec == 0)      qo[(size_t)(bh * 2048 + t) * 64 + e] = val;
                    else if (sec == 1) kpo[(size_t)(bh * 2048 + t) * 64 + e] = val;
                    else               vpto[(size_t)(bh * 64 + e) * 2048 + t] = val;
                } else {
                    out[(size_t)m * 1024 + ncol] = acc[i][j][r] + bp[ncol];
                }
            }
        }
    }
}

// ---------------------------------------------------------------- causal flash attention
// One wave = one 16-row Q chunk. No barriers; K/V read direct from L2.
// q,kp: [bh][t][64] bf16 ; vpT: [bh][64][2048] bf16 ; o: [b][t][h*64+kk] bf16
__global__ __launch_bounds__(64, 4) void attn_kernel(
    const unsigned short* __restrict__ qg, const unsigned short* __restrict__ kpg,
    const unsigned short* __restrict__ vptg, unsigned short* __restrict__ og) {
    // XCD-affinity mapping: xcd = bx&7 picks head group (4 heads -> 2MB KV per XCD L2);
    // chunk spread gives each CU uniformly-mixed triangular depths (balance +-9%).
    const int bx = blockIdx.x, by = blockIdx.y;
    const int xcd = bx & 7, sub = bx >> 3;          // sub in [0,16)
    const int bh = (by & 3) * 8 + xcd;              // head-batch index [0,32)
    const int chunk = (by >> 2) * 16 + sub;         // 16-row chunk [0,128)
    const int lane = threadIdx.x;
    const int g = lane >> 4, ln = lane & 15;

    __shared__ __align__(16) unsigned short pls[16][72];   // wave-private P, padded rows

    const unsigned short* qp = qg + (size_t)(bh * 2048 + chunk * 16 + ln) * 64;
    const bf16x8 qa0 = __builtin_bit_cast(bf16x8, *reinterpret_cast<const u16x8*>(qp + g * 8));
    const bf16x8 qa1 = __builtin_bit_cast(bf16x8, *reinterpret_cast<const u16x8*>(qp + 32 + g * 8));

    const unsigned short* kbase = kpg + (size_t)bh * 2048 * 64;
    const unsigned short* vbase = vptg + (size_t)bh * 64 * 2048;

    f32x4 o[4];
#pragma unroll
    for (int nt = 0; nt < 4; ++nt) o[nt] = (f32x4){0.f, 0.f, 0.f, 0.f};
    float mrow[4] = {-1e30f, -1e30f, -1e30f, -1e30f};
    float lrow[4] = {0.f, 0.f, 0.f, 0.f};
    const float scale = 0.125f;   // 1/sqrt(64)
    const int stmax = chunk >> 2;

    for (int st = 0; st <= stmax; ++st) {
        const int s0 = st * 64;
        // S = Q * KP^T : rows (q) = 4g+r, cols (s) = j*16+ln
        f32x4 sf[4];
#pragma unroll
        for (int j = 0; j < 4; ++j) {
            const unsigned short* krow = kbase + (size_t)(s0 + j * 16 + ln) * 64 + g * 8;
            bf16x8 bk0 = __builtin_bit_cast(bf16x8, *reinterpret_cast<const u16x8*>(krow));
            bf16x8 bk1 = __builtin_bit_cast(bf16x8, *reinterpret_cast<const u16x8*>(krow + 32));
            f32x4 a = (f32x4){0.f, 0.f, 0.f, 0.f};
            a = MFMA16(qa0, bk0, a);
            a = MFMA16(qa1, bk1, a);
            sf[j] = a;
        }
        // scale + causal mask (diagonal tile only)
#pragma unroll
        for (int j = 0; j < 4; ++j) {
#pragma unroll
            for (int r = 0; r < 4; ++r) {
                float v = sf[j][r] * scale;
                if (st == stmax) {
                    const int sg = s0 + j * 16 + ln;
                    const int qgl = chunk * 16 + 4 * g + r;
                    if (sg > qgl) v = -1e30f;
                }
                sf[j][r] = v;
            }
        }
        // online softmax
        float mp[4];
#pragma unroll
        for (int r = 0; r < 4; ++r) {
            float v = fmaxf(fmaxf(sf[0][r], sf[1][r]), fmaxf(sf[2][r], sf[3][r]));
            v = fmaxf(v, __shfl_xor(v, 1));
            v = fmaxf(v, __shfl_xor(v, 2));
            v = fmaxf(v, __shfl_xor(v, 4));
            v = fmaxf(v, __shfl_xor(v, 8));
            mp[r] = v;
        }
        float alpha[4];
#pragma unroll
        for (int r = 0; r < 4; ++r) {
            const float mn = fmaxf(mrow[r], mp[r]);
            alpha[r] = __expf(mrow[r] - mn);
            mrow[r] = mn;
        }
        float psum[4] = {0.f, 0.f, 0.f, 0.f};
#pragma unroll
        for (int j = 0; j < 4; ++j) {
#pragma unroll
            for (int r = 0; r < 4; ++r) {
                const float p = __expf(sf[j][r] - mrow[r]);
                psum[r] += p;
                pls[4 * g + r][j * 16 + ln] = f2bf(p);
            }
        }
#pragma unroll
        for (int r = 0; r < 4; ++r) {
            float v = psum[r];
            v += __shfl_xor(v, 1);
            v += __shfl_xor(v, 2);
            v += __shfl_xor(v, 4);
            v += __shfl_xor(v, 8);
            lrow[r] = lrow[r] * alpha[r] + v;
        }
#pragma unroll
        for (int nt = 0; nt < 4; ++nt)
#pragma unroll
            for (int r = 0; r < 4; ++r) o[nt][r] *= alpha[r];

        // O += P * VP  (A-frag from wave-private P tile, B-frag direct from vpT)
#pragma unroll
        for (int sk = 0; sk < 2; ++sk) {
            bf16x8 pa = __builtin_bit_cast(bf16x8, *reinterpret_cast<const u16x8*>(&pls[ln][sk * 32 + g * 8]));
#pragma unroll
            for (int nt = 0; nt < 4; ++nt) {
                bf16x8 vb = __builtin_bit_cast(bf16x8, *reinterpret_cast<const u16x8*>(
                    vbase + (size_t)(nt * 16 + ln) * 2048 + s0 + sk * 32 + g * 8));
                o[nt] = MFMA16(pa, vb, o[nt]);
            }
        }
    }

    const int b = bh >> 4, h = bh & 15;
#pragma unroll
    for (int r = 0; r < 4; ++r) {
        const float inv = 1.0f / lrow[r];
        const int t = chunk * 16 + 4 * g + r;
        const size_t base = (size_t)(b * 2048 + t) * 1024 + h * 64;
#pragma unroll
        for (int nt = 0; nt < 4; ++nt)
            og[base + nt * 16 + ln] = f2bf(o[nt][r] * inv);
    }
}

// ---------------------------------------------------------------- launch
extern "C" void kernel_launch(void* const* d_in, const int* in_sizes, int n_in,
                              void* d_out, int out_size, void* d_ws, size_t ws_size,
                              hipStream_t stream) {
    const float* x  = (const float*)d_in[0];
    const float* Wq = (const float*)d_in[1];
    const float* Wk = (const float*)d_in[2];
    const float* Wv = (const float*)d_in[3];
    const float* E  = (const float*)d_in[4];
    const float* F  = (const float*)d_in[5];
    const float* Wp = (const float*)d_in[6];
    const float* bp = (const float*)d_in[7];
    float* out = (float*)d_out;

    char* ws = (char*)d_ws;
    unsigned short* xb   = (unsigned short*)(ws);               // 4096x1024 bf16 (8 MB)
    unsigned short* wcat = (unsigned short*)(ws + 8388608);     // 3072x1024 bf16 (6 MB)
    unsigned short* qw   = (unsigned short*)(ws + 14680064);    // [32][2048][64] bf16 (8 MB)
    unsigned short* kpw  = (unsigned short*)(ws + 23068672);    // [32][2048][64] bf16 (8 MB)
    unsigned short* vptw = (unsigned short*)(ws + 31457280);    // [32][64][2048] bf16 (8 MB)
    unsigned short* ow   = (unsigned short*)(ws + 39845888);    // 4096x1024 bf16 (8 MB)
    unsigned short* wpb  = (unsigned short*)(ws + 48234496);    // 1024x1024 bf16 (2 MB)

    convert_f32_bf16<<<4096, 256, 0, stream>>>(x, xb, 1048576);
    convert_f32_bf16<<<1024, 256, 0, stream>>>(Wq, wcat, 262144);
    convert_f32_bf16<<<1024, 256, 0, stream>>>(Wp, wpb, 262144);
    build_wkev<<<8192, 256, 0, stream>>>(Wk, Wv, E, F, wcat);
    gemm_bt<0><<<dim3(32, 24), 256, 0, stream>>>(xb, wcat, 1024, qw, kpw, vptw, nullptr, nullptr);
    attn_kernel<<<dim3(128, 32), 64, 0, stream>>>(qw, kpw, vptw, ow);
    gemm_bt<1><<<dim3(32, 8), 256, 0, stream>>>(ow, wpb, 1024, nullptr, nullptr, nullptr, out, bp);
}

// Round 3
// 171.904 us; speedup vs baseline: 1.5746x; 1.5746x over previous
//
#include <hip/hip_runtime.h>

typedef __attribute__((ext_vector_type(8))) __bf16 bf16x8;
typedef __attribute__((ext_vector_type(4))) float f32x4;
typedef __attribute__((ext_vector_type(8))) unsigned short u16x8;

#define MFMA16(a, b, c) __builtin_amdgcn_mfma_f32_16x16x32_bf16((a), (b), (c), 0, 0, 0)

// async global->LDS, 16B per lane; dst must be wave-uniform base (lane*16B auto)
#define GLDS16(g, l) __builtin_amdgcn_global_load_lds( \
    (const __attribute__((address_space(1))) unsigned int*)(const void*)(g), \
    (__attribute__((address_space(3))) unsigned int*)(void*)(l), 16, 0, 0)

__device__ __forceinline__ unsigned short bfc(float f) {
    __bf16 h = (__bf16)f;
    return __builtin_bit_cast(unsigned short, h);
}

// ---------------------------------------------------------------- convert f32 -> bf16
__global__ void convert_f32_bf16(const float* __restrict__ src, unsigned short* __restrict__ dst, int n4) {
    int i = blockIdx.x * blockDim.x + threadIdx.x;
    if (i < n4) {
        float4 v = reinterpret_cast<const float4*>(src)[i];
        ushort4 o;
        o.x = bfc(v.x); o.y = bfc(v.y); o.z = bfc(v.z); o.w = bfc(v.w);
        reinterpret_cast<ushort4*>(dst)[i] = o;
    }
}

// ---------------------------------------------------------------- WkE / WvF fold (tiny)
__global__ void build_wkev(const float* __restrict__ Wk, const float* __restrict__ Wv,
                           const float* __restrict__ E, const float* __restrict__ F,
                           unsigned short* __restrict__ wcat) {
    int idx = blockIdx.x * 256 + threadIdx.x;          // 2M threads
    int c   = idx & 1023;
    int n2  = (idx >> 10) & 1023;
    int sel = idx >> 20;                                // 0 -> WkE, 1 -> WvF
    int h = n2 >> 6, kk = n2 & 63;
    const float* W  = sel ? Wv : Wk;
    const float* Ef = sel ? F : E;
    float acc = 0.f;
#pragma unroll 8
    for (int d = 0; d < 64; ++d)
        acc += W[(size_t)((h * 64 + d)) * 1024 + c] * Ef[(h * 64 + d) * 64 + kk];
    wcat[(size_t)(1024 + (sel << 10) + n2) * 1024 + c] = bfc(acc);
}

// ---------------------------------------------------------------- bf16 GEMM, B^T layout
// C[m][n] = sum_k A[m][k] * Bt[n][k]; staging via global_load_lds (m97 pattern)
template <int MODE>
__global__ __launch_bounds__(256) void gemm_bt(
    const unsigned short* __restrict__ A, const unsigned short* __restrict__ Bt, int K,
    unsigned short* __restrict__ qo, unsigned short* __restrict__ kpo, unsigned short* __restrict__ vpto,
    float* __restrict__ out, const float* __restrict__ bp) {
    __shared__ __align__(16) unsigned short As[128 * 32];
    __shared__ __align__(16) unsigned short Bs[128 * 32];
    const int tid = threadIdx.x;
    const int lane = tid & 63, wv = tid >> 6;
    const int g = lane >> 4, ln = lane & 15;
    const int wm = wv >> 1, wn = wv & 1;
    const int m0 = blockIdx.x * 128, n0 = blockIdx.y * 128;
    const int wvb = wv * 512;           // wave-uniform LDS base (shorts)

    f32x4 acc[4][4];
#pragma unroll
    for (int i = 0; i < 4; ++i)
#pragma unroll
        for (int j = 0; j < 4; ++j) acc[i][j] = (f32x4){0.f, 0.f, 0.f, 0.f};

    const int c0 = tid, c1 = 256 + tid;
    const int row0 = c0 >> 2, k80 = c0 & 3;
    const int row1 = c1 >> 2, k81 = c1 & 3;

    const int nk = K >> 5;
    for (int kt = 0; kt < nk; ++kt) {
        const int kb = kt * 32;
        __syncthreads();   // everyone done reading previous tile
        GLDS16(A  + (size_t)(m0 + row0) * K + kb + k80 * 8, As + wvb);
        GLDS16(A  + (size_t)(m0 + row1) * K + kb + k81 * 8, As + 2048 + wvb);
        GLDS16(Bt + (size_t)(n0 + row0) * K + kb + k80 * 8, Bs + wvb);
        GLDS16(Bt + (size_t)(n0 + row1) * K + kb + k81 * 8, Bs + 2048 + wvb);
        __syncthreads();   // drain vmcnt + barrier -> tile visible
        bf16x8 af[4], bfr[4];
#pragma unroll
        for (int i = 0; i < 4; ++i)
            af[i] = __builtin_bit_cast(bf16x8, *reinterpret_cast<const u16x8*>(As + (wm * 64 + i * 16 + ln) * 32 + g * 8));
#pragma unroll
        for (int j = 0; j < 4; ++j)
            bfr[j] = __builtin_bit_cast(bf16x8, *reinterpret_cast<const u16x8*>(Bs + (wn * 64 + j * 16 + ln) * 32 + g * 8));
#pragma unroll
        for (int i = 0; i < 4; ++i)
#pragma unroll
            for (int j = 0; j < 4; ++j)
                acc[i][j] = MFMA16(af[i], bfr[j], acc[i][j]);
    }

#pragma unroll
    for (int i = 0; i < 4; ++i) {
        const int mbase = m0 + wm * 64 + i * 16 + 4 * g;
#pragma unroll
        for (int j = 0; j < 4; ++j) {
            const int ncol = n0 + wn * 64 + j * 16 + ln;
#pragma unroll
            for (int r = 0; r < 4; ++r) {
                const int m = mbase + r;
                if (MODE == 0) {
                    const int b = m >> 11, t = m & 2047;
                    const int sec = ncol >> 10, nn = ncol & 1023;
                    const int h = nn >> 6, e = nn & 63;
                    const int bh = b * 16 + h;
                    unsigned short val = bfc(acc[i][j][r]);
                    if (sec == 0)      qo[(size_t)(bh * 2048 + t) * 64 + e] = val;
                    else if (sec == 1) kpo[(size_t)(bh * 2048 + t) * 64 + e] = val;
                    else               vpto[(size_t)(bh * 64 + e) * 2048 + t] = val;
                } else {
                    out[(size_t)m * 1024 + ncol] = acc[i][j][r] + bp[ncol];
                }
            }
        }
    }
}

// ---------------------------------------------------------------- causal flash attention
// 8-wave block; waves 0-3 own q-tile p, waves 4-7 own q-tile 31-p (fold-paired triangle).
// Shared double-buffered K/V staging via global_load_lds; 1 barrier per KV tile.
// q,kp: [bh][t][64] bf16 ; vpT: [bh][64][2048] bf16 ; o: [b][t][h*64+kk] bf16
__global__ __launch_bounds__(512, 4) void attn_kernel(
    const unsigned short* __restrict__ qg, const unsigned short* __restrict__ kpg,
    const unsigned short* __restrict__ vptg, unsigned short* __restrict__ og) {
    const int raw = blockIdx.y * 16 + blockIdx.x;      // 512 blocks
    const int xcd = raw & 7, idx = raw >> 3;           // XCD-affinity: 4 heads per XCD
    const int bh  = xcd * 4 + (idx & 3);               // [0,32)
    const int p   = idx >> 2;                          // pair [0,16)
    const int qtA = p, qtB = 31 - p;
    const int tid = threadIdx.x;
    const int wv = tid >> 6, lane = tid & 63;
    const int g = lane >> 4, ln = lane & 15;
    const int myqt = (wv < 4) ? qtA : qtB;
    const int stBig = qtB;

    __shared__ __align__(16) unsigned short kps[2][4096];
    __shared__ __align__(16) unsigned short vps[2][4096];
    __shared__ __align__(16) unsigned short pls[8][16][72];

    const unsigned short* kbase = kpg  + (size_t)bh * 131072;
    const unsigned short* vbase = vptg + (size_t)bh * 131072;

    const unsigned short* qp = qg + ((size_t)bh * 2048 + myqt * 64 + (wv & 3) * 16 + ln) * 64;
    const bf16x8 qa0 = __builtin_bit_cast(bf16x8, *reinterpret_cast<const u16x8*>(qp + g * 8));
    const bf16x8 qa1 = __builtin_bit_cast(bf16x8, *reinterpret_cast<const u16x8*>(qp + 32 + g * 8));

    const u16x8 onesu = {0x3F80, 0x3F80, 0x3F80, 0x3F80, 0x3F80, 0x3F80, 0x3F80, 0x3F80};
    const bf16x8 onesf = __builtin_bit_cast(bf16x8, onesu);

    f32x4 o[4];
#pragma unroll
    for (int nt = 0; nt < 4; ++nt) o[nt] = (f32x4){0.f, 0.f, 0.f, 0.f};
    f32x4 lacc = (f32x4){0.f, 0.f, 0.f, 0.f};
    float mrow[4] = {-1e30f, -1e30f, -1e30f, -1e30f};
    const float scale = 0.125f;       // 1/sqrt(64)
    const float L2E = 1.44269504f;

    const int srow_s = tid >> 3, sch = (tid & 7) ^ (srow_s & 7);   // staging coords (pre-swizzled src)
    auto stage = [&](int b, int st) {
        const int s0 = st * 64;
        GLDS16(kbase + (size_t)(s0 + srow_s) * 64 + sch * 8, &kps[b][wv * 512]);
        GLDS16(vbase + (size_t)srow_s * 2048 + s0 + sch * 8, &vps[b][wv * 512]);
    };

    stage(0, 0);
    for (int st = 0; st <= stBig; ++st) {
        const int cur = st & 1;
        __syncthreads();                       // tile st landed & prev reads done
        if (st < stBig) stage(cur ^ 1, st + 1);   // prefetch under this tile's compute
        if (st <= myqt) {
            // ---- S = Q * KP^T : D rows = q (4g+r), cols = s (j*16+ln)
            f32x4 sf[4];
#pragma unroll
            for (int j = 0; j < 4; ++j) {
                const int srow = j * 16 + ln;
                const unsigned short* kb8 = &kps[cur][srow * 64];
                bf16x8 bk0 = __builtin_bit_cast(bf16x8, *reinterpret_cast<const u16x8*>(kb8 + ((g) ^ (srow & 7)) * 8));
                bf16x8 bk1 = __builtin_bit_cast(bf16x8, *reinterpret_cast<const u16x8*>(kb8 + ((4 + g) ^ (srow & 7)) * 8));
                f32x4 a = (f32x4){0.f, 0.f, 0.f, 0.f};
                a = MFMA16(qa0, bk0, a);
                a = MFMA16(qa1, bk1, a);
                sf[j] = a;
            }
            // ---- scale + causal mask (diagonal tile only)
#pragma unroll
            for (int j = 0; j < 4; ++j)
#pragma unroll
                for (int r = 0; r < 4; ++r) {
                    float v = sf[j][r] * scale;
                    if (st == myqt) {
                        const int sg = st * 64 + j * 16 + ln;
                        const int qgl = myqt * 64 + (wv & 3) * 16 + 4 * g + r;
                        if (sg > qgl) v = -1e30f;
                    }
                    sf[j][r] = v;
                }
            // ---- row max (tile)
            float mp[4];
#pragma unroll
            for (int r = 0; r < 4; ++r) {
                float v = fmaxf(fmaxf(sf[0][r], sf[1][r]), fmaxf(sf[2][r], sf[3][r]));
                v = fmaxf(v, __shfl_xor(v, 1));
                v = fmaxf(v, __shfl_xor(v, 2));
                v = fmaxf(v, __shfl_xor(v, 4));
                v = fmaxf(v, __shfl_xor(v, 8));
                mp[r] = v;
            }
            // ---- defer-max rescale (THR=8)
            float dm = mp[0] - mrow[0];
            dm = fmaxf(dm, mp[1] - mrow[1]);
            dm = fmaxf(dm, mp[2] - mrow[2]);
            dm = fmaxf(dm, mp[3] - mrow[3]);
            if (__any(dm > 8.0f)) {
#pragma unroll
                for (int r = 0; r < 4; ++r) {
                    const float mn = fmaxf(mrow[r], mp[r]);
                    const float a = __builtin_exp2f((mrow[r] - mn) * L2E);
                    mrow[r] = mn;
#pragma unroll
                    for (int nt = 0; nt < 4; ++nt) o[nt][r] *= a;
                    lacc[r] *= a;
                }
            }
            // ---- P = exp(S - m), write wave-private transpose tile
#pragma unroll
            for (int j = 0; j < 4; ++j)
#pragma unroll
                for (int r = 0; r < 4; ++r) {
                    const float pv = __builtin_exp2f((sf[j][r] - mrow[r]) * L2E);
                    pls[wv][4 * g + r][j * 16 + ln] = bfc(pv);
                }
            // ---- O += P*V ; l += P*ones (row-sum via MFMA)
#pragma unroll
            for (int sk = 0; sk < 2; ++sk) {
                bf16x8 pa = __builtin_bit_cast(bf16x8, *reinterpret_cast<const u16x8*>(&pls[wv][ln][sk * 32 + g * 8]));
                lacc = MFMA16(pa, onesf, lacc);
#pragma unroll
                for (int nt = 0; nt < 4; ++nt) {
                    const int vrow = nt * 16 + ln;
                    bf16x8 vb = __builtin_bit_cast(bf16x8, *reinterpret_cast<const u16x8*>(
                        &vps[cur][vrow * 64 + (((sk * 4 + g) ^ (vrow & 7)) * 8)]));
                    o[nt] = MFMA16(pa, vb, o[nt]);
                }
            }
        }
    }

    const int b = bh >> 4, h = bh & 15;
#pragma unroll
    for (int r = 0; r < 4; ++r) {
        const float inv = 1.0f / lacc[r];
        const int t = myqt * 64 + (wv & 3) * 16 + 4 * g + r;
        const size_t base = (size_t)(b * 2048 + t) * 1024 + h * 64;
#pragma unroll
        for (int nt = 0; nt < 4; ++nt)
            og[base + nt * 16 + ln] = bfc(o[nt][r] * inv);
    }
}

// ---------------------------------------------------------------- launch
extern "C" void kernel_launch(void* const* d_in, const int* in_sizes, int n_in,
                              void* d_out, int out_size, void* d_ws, size_t ws_size,
                              hipStream_t stream) {
    const float* x  = (const float*)d_in[0];
    const float* Wq = (const float*)d_in[1];
    const float* Wk = (const float*)d_in[2];
    const float* Wv = (const float*)d_in[3];
    const float* E  = (const float*)d_in[4];
    const float* F  = (const float*)d_in[5];
    const float* Wp = (const float*)d_in[6];
    const float* bp = (const float*)d_in[7];
    float* out = (float*)d_out;

    char* ws = (char*)d_ws;
    unsigned short* xb   = (unsigned short*)(ws);               // 4096x1024 bf16 (8 MB)
    unsigned short* wcat = (unsigned short*)(ws + 8388608);     // 3072x1024 bf16 (6 MB)
    unsigned short* qw   = (unsigned short*)(ws + 14680064);    // [32][2048][64] bf16 (8 MB)
    unsigned short* kpw  = (unsigned short*)(ws + 23068672);    // [32][2048][64] bf16 (8 MB)
    unsigned short* vptw = (unsigned short*)(ws + 31457280);    // [32][64][2048] bf16 (8 MB)
    unsigned short* ow   = (unsigned short*)(ws + 39845888);    // 4096x1024 bf16 (8 MB)
    unsigned short* wpb  = (unsigned short*)(ws + 48234496);    // 1024x1024 bf16 (2 MB)

    convert_f32_bf16<<<4096, 256, 0, stream>>>(x, xb, 1048576);
    convert_f32_bf16<<<1024, 256, 0, stream>>>(Wq, wcat, 262144);
    convert_f32_bf16<<<1024, 256, 0, stream>>>(Wp, wpb, 262144);
    build_wkev<<<8192, 256, 0, stream>>>(Wk, Wv, E, F, wcat);
    gemm_bt<0><<<dim3(32, 24), 256, 0, stream>>>(xb, wcat, 1024, qw, kpw, vptw, nullptr, nullptr);
    attn_kernel<<<dim3(16, 32), 512, 0, stream>>>(qw, kpw, vptw, ow);
    gemm_bt<1><<<dim3(32, 8), 256, 0, stream>>>(ow, wpb, 1024, nullptr, nullptr, nullptr, out, bp);
}

// Round 4
// 151.495 us; speedup vs baseline: 1.7867x; 1.1347x over previous
//
#include <hip/hip_runtime.h>

typedef __attribute__((ext_vector_type(8))) __bf16 bf16x8;
typedef __attribute__((ext_vector_type(4))) float f32x4;
typedef __attribute__((ext_vector_type(16))) float f32x16;
typedef __attribute__((ext_vector_type(8))) unsigned short u16x8;

#define MFMA16(a, b, c) __builtin_amdgcn_mfma_f32_16x16x32_bf16((a), (b), (c), 0, 0, 0)
#define MFMA32(a, b, c) __builtin_amdgcn_mfma_f32_32x32x16_bf16((a), (b), (c), 0, 0, 0)

// async global->LDS, 16B per lane; dst must be wave-uniform base (lane*16B auto)
#define GLDS16(g, l) __builtin_amdgcn_global_load_lds( \
    (const __attribute__((address_space(1))) unsigned int*)(const void*)(g), \
    (__attribute__((address_space(3))) unsigned int*)(void*)(l), 16, 0, 0)

__device__ __forceinline__ unsigned short bfc(float f) {
    __bf16 h = (__bf16)f;
    return __builtin_bit_cast(unsigned short, h);
}

// ---------------------------------------------------------------- convert f32 -> bf16
__global__ void convert_f32_bf16(const float* __restrict__ src, unsigned short* __restrict__ dst, int n4) {
    int i = blockIdx.x * blockDim.x + threadIdx.x;
    if (i < n4) {
        float4 v = reinterpret_cast<const float4*>(src)[i];
        ushort4 o;
        o.x = bfc(v.x); o.y = bfc(v.y); o.z = bfc(v.z); o.w = bfc(v.w);
        reinterpret_cast<ushort4*>(dst)[i] = o;
    }
}

// ---------------------------------------------------------------- WkE / WvF fold
// block: (sel, h, c-strip of 128). E_h staged in LDS; thread owns 8kk x 4c.
__global__ __launch_bounds__(256) void build_wkev(
    const float* __restrict__ Wk, const float* __restrict__ Wv,
    const float* __restrict__ E, const float* __restrict__ F,
    unsigned short* __restrict__ wcat) {
    __shared__ float Els[4096];          // E_h: [64 d][64 kk] f32
    const int bx = blockIdx.x;           // 256 blocks
    const int sel = bx >> 7, h = (bx >> 3) & 15, cs = bx & 7;
    const int tid = threadIdx.x;
    const int ko = tid >> 5, cq = tid & 31;
    const int c = cs * 128 + cq * 4;

    const float* W  = sel ? Wv : Wk;
    const float* Ef = (sel ? F : E) + (size_t)h * 4096;
#pragma unroll
    for (int i = tid; i < 1024; i += 256)
        reinterpret_cast<float4*>(Els)[i] = reinterpret_cast<const float4*>(Ef)[i];
    __syncthreads();

    float acc[8][4];
#pragma unroll
    for (int j = 0; j < 8; ++j)
#pragma unroll
        for (int t = 0; t < 4; ++t) acc[j][t] = 0.f;

#pragma unroll 4
    for (int d = 0; d < 64; ++d) {
        float4 wv4 = *reinterpret_cast<const float4*>(&W[(size_t)(h * 64 + d) * 1024 + c]);
        float4 e0 = *reinterpret_cast<const float4*>(&Els[d * 64 + ko * 8]);
        float4 e1 = *reinterpret_cast<const float4*>(&Els[d * 64 + ko * 8 + 4]);
        float ev[8] = {e0.x, e0.y, e0.z, e0.w, e1.x, e1.y, e1.z, e1.w};
#pragma unroll
        for (int j = 0; j < 8; ++j) {
            acc[j][0] = fmaf(ev[j], wv4.x, acc[j][0]);
            acc[j][1] = fmaf(ev[j], wv4.y, acc[j][1]);
            acc[j][2] = fmaf(ev[j], wv4.z, acc[j][2]);
            acc[j][3] = fmaf(ev[j], wv4.w, acc[j][3]);
        }
    }
#pragma unroll
    for (int j = 0; j < 8; ++j) {
        const int row = 1024 + (sel << 10) + h * 64 + ko * 8 + j;
        ushort4 o;
        o.x = bfc(acc[j][0]); o.y = bfc(acc[j][1]); o.z = bfc(acc[j][2]); o.w = bfc(acc[j][3]);
        *reinterpret_cast<ushort4*>(&wcat[(size_t)row * 1024 + c]) = o;
    }
}

// ---------------------------------------------------------------- bf16 GEMM, B^T layout
template <int MODE>
__global__ __launch_bounds__(256) void gemm_bt(
    const unsigned short* __restrict__ A, const unsigned short* __restrict__ Bt, int K,
    unsigned short* __restrict__ qo, unsigned short* __restrict__ kpo, unsigned short* __restrict__ vpto,
    float* __restrict__ out, const float* __restrict__ bp) {
    __shared__ __align__(16) unsigned short As[128 * 32];
    __shared__ __align__(16) unsigned short Bs[128 * 32];
    const int tid = threadIdx.x;
    const int lane = tid & 63, wv = tid >> 6;
    const int g = lane >> 4, ln = lane & 15;
    const int wm = wv >> 1, wn = wv & 1;
    const int m0 = blockIdx.x * 128, n0 = blockIdx.y * 128;
    const int wvb = wv * 512;

    f32x4 acc[4][4];
#pragma unroll
    for (int i = 0; i < 4; ++i)
#pragma unroll
        for (int j = 0; j < 4; ++j) acc[i][j] = (f32x4){0.f, 0.f, 0.f, 0.f};

    const int c0 = tid, c1 = 256 + tid;
    const int row0 = c0 >> 2, k80 = c0 & 3;
    const int row1 = c1 >> 2, k81 = c1 & 3;

    const int nk = K >> 5;
    for (int kt = 0; kt < nk; ++kt) {
        const int kb = kt * 32;
        __syncthreads();
        GLDS16(A  + (size_t)(m0 + row0) * K + kb + k80 * 8, As + wvb);
        GLDS16(A  + (size_t)(m0 + row1) * K + kb + k81 * 8, As + 2048 + wvb);
        GLDS16(Bt + (size_t)(n0 + row0) * K + kb + k80 * 8, Bs + wvb);
        GLDS16(Bt + (size_t)(n0 + row1) * K + kb + k81 * 8, Bs + 2048 + wvb);
        __syncthreads();
        bf16x8 af[4], bfr[4];
#pragma unroll
        for (int i = 0; i < 4; ++i)
            af[i] = __builtin_bit_cast(bf16x8, *reinterpret_cast<const u16x8*>(As + (wm * 64 + i * 16 + ln) * 32 + g * 8));
#pragma unroll
        for (int j = 0; j < 4; ++j)
            bfr[j] = __builtin_bit_cast(bf16x8, *reinterpret_cast<const u16x8*>(Bs + (wn * 64 + j * 16 + ln) * 32 + g * 8));
#pragma unroll
        for (int i = 0; i < 4; ++i)
#pragma unroll
            for (int j = 0; j < 4; ++j)
                acc[i][j] = MFMA16(af[i], bfr[j], acc[i][j]);
    }

#pragma unroll
    for (int i = 0; i < 4; ++i) {
        const int mbase = m0 + wm * 64 + i * 16 + 4 * g;
#pragma unroll
        for (int j = 0; j < 4; ++j) {
            const int ncol = n0 + wn * 64 + j * 16 + ln;
#pragma unroll
            for (int r = 0; r < 4; ++r) {
                const int m = mbase + r;
                if (MODE == 0) {
                    const int b = m >> 11, t = m & 2047;
                    const int sec = ncol >> 10, nn = ncol & 1023;
                    const int h = nn >> 6, e = nn & 63;
                    const int bh = b * 16 + h;
                    unsigned short val = bfc(acc[i][j][r]);
                    if (sec == 0)      qo[(size_t)(bh * 2048 + t) * 64 + e] = val;
                    else if (sec == 1) kpo[(size_t)(bh * 2048 + t) * 64 + e] = val;
                    else               vpto[(size_t)(bh * 64 + e) * 2048 + t] = val;
                } else {
                    out[(size_t)m * 1024 + ncol] = acc[i][j][r] + bp[ncol];
                }
            }
        }
    }
}

// ---------------------------------------------------------------- causal flash attention
// block = one 64-row q-tile, 2 waves x 32 q-rows, 32x32 MFMA, in-register P.
// Swapped QK^T: S^T[s][q], col=q=lane&31 -> softmax lane-local.
// q,kp: [bh][t][64] bf16 ; vpT: [bh][64][2048] bf16 ; o: [b][t][h*64+kk] bf16
__global__ __launch_bounds__(128, 2) void attn_kernel(
    const unsigned short* __restrict__ qg, const unsigned short* __restrict__ kpg,
    const unsigned short* __restrict__ vptg, unsigned short* __restrict__ og) {
    const int bx = blockIdx.x;
    const int qt = 31 - blockIdx.y;                // long blocks dispatched first
    const int bh = (bx & 7) * 4 + (bx >> 3);       // XCD-affinity: 4 heads per XCD
    const int tid = threadIdx.x;
    const int wv = tid >> 6, lane = tid & 63;
    const int r31 = lane & 31, hi = lane >> 5, l7 = lane & 7;

    __shared__ __align__(16) unsigned short kps[2][4096];   // [64 s][8 chunks swz]
    __shared__ __align__(16) unsigned short vps[2][4096];   // [64 v][8 chunks swz]

    const unsigned short* kbase = kpg  + (size_t)bh * 131072;
    const unsigned short* vbase = vptg + (size_t)bh * 131072;

    // Q B-frags: q-row = qt*64+wv*32+r31; window w: d = 16w + 8hi + j
    const int qrow = qt * 64 + wv * 32 + r31;
    const unsigned short* qp = qg + ((size_t)bh * 2048 + qrow) * 64 + 8 * hi;
    bf16x8 qf[4];
#pragma unroll
    for (int w = 0; w < 4; ++w)
        qf[w] = __builtin_bit_cast(bf16x8, *reinterpret_cast<const u16x8*>(qp + 16 * w));

    f32x16 oT0 = {0,0,0,0,0,0,0,0,0,0,0,0,0,0,0,0};
    f32x16 oT1 = {0,0,0,0,0,0,0,0,0,0,0,0,0,0,0,0};
    float mrow = -1e30f, lacc = 0.f;
    const float L2E = 1.44269504f;
    const float CS  = 0.18033688f;     // 0.125 * log2(e)

    auto stage = [&](int buf, int st) {
        const int s0 = st * 64;
#pragma unroll
        for (int rep = 0; rep < 4; ++rep) {
            const int row = rep * 16 + wv * 8 + (lane >> 3);
            const int cg = (lane & 7) ^ (lane >> 3);   // row&7 == lane>>3 here
            GLDS16(kbase + (size_t)(s0 + row) * 64 + cg * 8, &kps[buf][(rep * 16 + wv * 8) * 64]);
            GLDS16(vbase + (size_t)row * 2048 + s0 + cg * 8, &vps[buf][(rep * 16 + wv * 8) * 64]);
        }
    };

    stage(0, 0);
    for (int st = 0; st <= qt; ++st) {
        const int cur = st & 1;
        __syncthreads();                 // tile st landed (vmcnt drained) & prev reads done
        if (st < qt) stage(cur ^ 1, st + 1);

        const bool diag = (st == qt);
        const bool skip1 = diag && (wv == 0);   // sblk1 fully masked for wave 0 on diag

        // ---- S^T = KP * Q^T : D[row=s][col=q]
        f32x16 sA0 = {0,0,0,0,0,0,0,0,0,0,0,0,0,0,0,0};
        f32x16 sA1 = {0,0,0,0,0,0,0,0,0,0,0,0,0,0,0,0};
#pragma unroll
        for (int w = 0; w < 4; ++w) {
            bf16x8 k0 = __builtin_bit_cast(bf16x8, *reinterpret_cast<const u16x8*>(
                &kps[cur][r31 * 64 + (((2 * w + hi) ^ l7) * 8)]));
            sA0 = MFMA32(k0, qf[w], sA0);
        }
        if (!skip1) {
#pragma unroll
            for (int w = 0; w < 4; ++w) {
                bf16x8 k1 = __builtin_bit_cast(bf16x8, *reinterpret_cast<const u16x8*>(
                    &kps[cur][(32 + r31) * 64 + (((2 * w + hi) ^ l7) * 8)]));
                sA1 = MFMA32(k1, qf[w], sA1);
            }
        }

        // ---- causal mask on the active diagonal sblk (sb == wv): s_off > q_off
        if (diag) {
#pragma unroll
            for (int reg = 0; reg < 16; ++reg) {
                const int oc = (reg & 3) + 8 * (reg >> 2);
                if (wv == 0) { if (oc + 4 * hi > r31) sA0[reg] = -3e38f; }
                else         { if (oc + 4 * hi > r31) sA1[reg] = -3e38f; }
            }
        }

        // ---- row max (lane-local + partner)
        float mp = sA0[0];
#pragma unroll
        for (int reg = 1; reg < 16; ++reg) mp = fmaxf(mp, sA0[reg]);
        if (!skip1) {
#pragma unroll
            for (int reg = 0; reg < 16; ++reg) mp = fmaxf(mp, sA1[reg]);
        }
        mp = fmaxf(mp, __shfl_xor(mp, 32));
        mp *= 0.125f;                       // scaled units

        // ---- defer-max rescale (THR=8)
        if (__any(mp - mrow > 8.0f)) {
            const float mn = fmaxf(mrow, mp);
            const float al = __builtin_exp2f((mrow - mn) * L2E);
            mrow = mn;
#pragma unroll
            for (int reg = 0; reg < 16; ++reg) { oT0[reg] *= al; oT1[reg] *= al; }
            lacc *= al;
        }
        const float t2 = mrow * L2E;

        // ---- P = exp2(S*CS - t2), row-sum, pack to bf16 + permlane swap -> PV B-frags
        float p0[16], p1[16];
#pragma unroll
        for (int reg = 0; reg < 16; ++reg) p0[reg] = __builtin_exp2f(fmaf(sA0[reg], CS, -t2));
        float ls0 = 0.f, ls1 = 0.f, ls2 = 0.f, ls3 = 0.f;
#pragma unroll
        for (int reg = 0; reg < 16; reg += 4) {
            ls0 += p0[reg]; ls1 += p0[reg + 1]; ls2 += p0[reg + 2]; ls3 += p0[reg + 3];
        }
        if (!skip1) {
#pragma unroll
            for (int reg = 0; reg < 16; ++reg) p1[reg] = __builtin_exp2f(fmaf(sA1[reg], CS, -t2));
#pragma unroll
            for (int reg = 0; reg < 16; reg += 4) {
                ls0 += p1[reg]; ls1 += p1[reg + 1]; ls2 += p1[reg + 2]; ls3 += p1[reg + 3];
            }
        }
        float ls = (ls0 + ls1) + (ls2 + ls3);
        ls += __shfl_xor(ls, 32);
        lacc += ls;

        unsigned int w0[8], w1[8];
#pragma unroll
        for (int i = 0; i < 8; ++i)
            asm("v_cvt_pk_bf16_f32 %0, %1, %2" : "=v"(w0[i]) : "v"(p0[2 * i]), "v"(p0[2 * i + 1]));
        asm volatile("v_permlane32_swap_b32 %0, %1" : "+v"(w0[0]), "+v"(w0[2]));
        asm volatile("v_permlane32_swap_b32 %0, %1" : "+v"(w0[1]), "+v"(w0[3]));
        asm volatile("v_permlane32_swap_b32 %0, %1" : "+v"(w0[4]), "+v"(w0[6]));
        asm volatile("v_permlane32_swap_b32 %0, %1" : "+v"(w0[5]), "+v"(w0[7]));
        if (!skip1) {
#pragma unroll
            for (int i = 0; i < 8; ++i)
                asm("v_cvt_pk_bf16_f32 %0, %1, %2" : "=v"(w1[i]) : "v"(p1[2 * i]), "v"(p1[2 * i + 1]));
            asm volatile("v_permlane32_swap_b32 %0, %1" : "+v"(w1[0]), "+v"(w1[2]));
            asm volatile("v_permlane32_swap_b32 %0, %1" : "+v"(w1[1]), "+v"(w1[3]));
            asm volatile("v_permlane32_swap_b32 %0, %1" : "+v"(w1[4]), "+v"(w1[6]));
            asm volatile("v_permlane32_swap_b32 %0, %1" : "+v"(w1[5]), "+v"(w1[7]));
        }

        // ---- O^T += V^T-frag * P-frag : D[row=v][col=q]
#pragma unroll
        for (int w = 0; w < 2; ++w) {       // s-windows 0,1 (sblk0)
            bf16x8 pa = __builtin_bit_cast(bf16x8, (uint4){w0[4 * w], w0[4 * w + 1], w0[4 * w + 2], w0[4 * w + 3]});
            bf16x8 v0 = __builtin_bit_cast(bf16x8, *reinterpret_cast<const u16x8*>(
                &vps[cur][r31 * 64 + (((2 * w + hi) ^ l7) * 8)]));
            oT0 = MFMA32(v0, pa, oT0);
            bf16x8 v1 = __builtin_bit_cast(bf16x8, *reinterpret_cast<const u16x8*>(
                &vps[cur][(32 + r31) * 64 + (((2 * w + hi) ^ l7) * 8)]));
            oT1 = MFMA32(v1, pa, oT1);
        }
        if (!skip1) {
#pragma unroll
            for (int w = 2; w < 4; ++w) {   // s-windows 2,3 (sblk1)
                bf16x8 pa = __builtin_bit_cast(bf16x8, (uint4){w1[4 * (w - 2)], w1[4 * (w - 2) + 1], w1[4 * (w - 2) + 2], w1[4 * (w - 2) + 3]});
                bf16x8 v0 = __builtin_bit_cast(bf16x8, *reinterpret_cast<const u16x8*>(
                    &vps[cur][r31 * 64 + (((2 * w + hi) ^ l7) * 8)]));
                oT0 = MFMA32(v0, pa, oT0);
                bf16x8 v1 = __builtin_bit_cast(bf16x8, *reinterpret_cast<const u16x8*>(
                    &vps[cur][(32 + r31) * 64 + (((2 * w + hi) ^ l7) * 8)]));
                oT1 = MFMA32(v1, pa, oT1);
            }
        }
    }

    // ---- epilogue: divide, pack, LDS-transpose to row-major, coalesced store
    __syncthreads();    // both waves done with kps/vps
    const float inv = 1.0f / lacc;
#pragma unroll
    for (int reg = 0; reg < 16; ++reg) { oT0[reg] *= inv; oT1[reg] *= inv; }

    unsigned int* tr = reinterpret_cast<unsigned int*>(wv ? (void*)kps[1] : (void*)kps[0]);  // [32 q][33] u32
#pragma unroll
    for (int i = 0; i < 8; ++i) {
        unsigned int wda, wdb;
        asm("v_cvt_pk_bf16_f32 %0, %1, %2" : "=v"(wda) : "v"(oT0[2 * i]), "v"(oT0[2 * i + 1]));
        asm("v_cvt_pk_bf16_f32 %0, %1, %2" : "=v"(wdb) : "v"(oT1[2 * i]), "v"(oT1[2 * i + 1]));
        const int col = (i & 1) + 4 * (i >> 1) + 2 * hi;
        tr[r31 * 33 + col] = wda;          // vb=0
        tr[r31 * 33 + 16 + col] = wdb;     // vb=1
    }
    const int b = bh >> 4, h = bh & 15;
    const int t = qt * 64 + wv * 32 + r31;
    const size_t gb = ((size_t)(b * 2048 + t)) * 1024 + h * 64 + 32 * hi;
#pragma unroll
    for (int cc = 0; cc < 4; ++cc) {
        uint4 v = *reinterpret_cast<uint4*>(&tr[r31 * 33 + 16 * hi + 4 * cc]);
        *reinterpret_cast<uint4*>(&og[gb + 8 * cc]) = v;
    }
}

// ---------------------------------------------------------------- launch
extern "C" void kernel_launch(void* const* d_in, const int* in_sizes, int n_in,
                              void* d_out, int out_size, void* d_ws, size_t ws_size,
                              hipStream_t stream) {
    const float* x  = (const float*)d_in[0];
    const float* Wq = (const float*)d_in[1];
    const float* Wk = (const float*)d_in[2];
    const float* Wv = (const float*)d_in[3];
    const float* E  = (const float*)d_in[4];
    const float* F  = (const float*)d_in[5];
    const float* Wp = (const float*)d_in[6];
    const float* bp = (const float*)d_in[7];
    float* out = (float*)d_out;

    char* ws = (char*)d_ws;
    unsigned short* xb   = (unsigned short*)(ws);               // 4096x1024 bf16 (8 MB)
    unsigned short* wcat = (unsigned short*)(ws + 8388608);     // 3072x1024 bf16 (6 MB)
    unsigned short* qw   = (unsigned short*)(ws + 14680064);    // [32][2048][64] bf16 (8 MB)
    unsigned short* kpw  = (unsigned short*)(ws + 23068672);    // [32][2048][64] bf16 (8 MB)
    unsigned short* vptw = (unsigned short*)(ws + 31457280);    // [32][64][2048] bf16 (8 MB)
    unsigned short* ow   = (unsigned short*)(ws + 39845888);    // 4096x1024 bf16 (8 MB)
    unsigned short* wpb  = (unsigned short*)(ws + 48234496);    // 1024x1024 bf16 (2 MB)

    convert_f32_bf16<<<4096, 256, 0, stream>>>(x, xb, 1048576);
    convert_f32_bf16<<<1024, 256, 0, stream>>>(Wq, wcat, 262144);
    convert_f32_bf16<<<1024, 256, 0, stream>>>(Wp, wpb, 262144);
    build_wkev<<<256, 256, 0, stream>>>(Wk, Wv, E, F, wcat);
    gemm_bt<0><<<dim3(32, 24), 256, 0, stream>>>(xb, wcat, 1024, qw, kpw, vptw, nullptr, nullptr);
    attn_kernel<<<dim3(32, 32), 128, 0, stream>>>(qw, kpw, vptw, ow);
    gemm_bt<1><<<dim3(32, 8), 256, 0, stream>>>(ow, wpb, 1024, nullptr, nullptr, nullptr, out, bp);
}